// Round 7
// baseline (181.218 us; speedup 1.0000x reference)
//
#include <hip/hip_runtime.h>
#include <cstddef>
#include <cstdint>

typedef __attribute__((ext_vector_type(8))) short short8;
typedef __attribute__((ext_vector_type(4))) float f32x4;

namespace {
constexpr int B_   = 2;
constexpr int HW   = 16384;
constexpr int NTOT = 21504;
constexpr float SCALE = 0.088388347648318447f;  // 128^-0.5
}

__device__ __forceinline__ unsigned short f2bf(float f) {
    unsigned u = __builtin_bit_cast(unsigned, f);
    u += 0x7fffu + ((u >> 16) & 1u);
    return (unsigned short)(u >> 16);
}
__device__ __forceinline__ float bf2f(unsigned short h) {
    return __builtin_bit_cast(float, (unsigned)h << 16);
}
__device__ __forceinline__ float blo(unsigned u) {
    return __builtin_bit_cast(float, u << 16);
}
__device__ __forceinline__ float bhi(unsigned u) {
    return __builtin_bit_cast(float, u & 0xffff0000u);
}
__device__ __forceinline__ unsigned pk2(float a, float b) {
    return (unsigned)f2bf(a) | ((unsigned)f2bf(b) << 16);
}
__device__ __forceinline__ void gload_lds16(const void* g, void* l) {
    __builtin_amdgcn_global_load_lds(
        (const __attribute__((address_space(1))) void*)g,
        (__attribute__((address_space(3))) void*)l, 16, 0, 0);
}

// ---------------------------------------------------------------------------
// tp_k: one dispatch, three jobs by block range.
//   blocks 0..519    : NCHW fp32 -> pixel-major bf16 (B,130,130,256), borders 0
//   blocks 520..1095 : pack combined weights (key_w@conv_w | query_w@conv_w)
//   block 1096       : combined bias
// ---------------------------------------------------------------------------
__global__ __launch_bounds__(256) void tp_k(
    const float* __restrict__ feats, const float* __restrict__ cw,
    const float* __restrict__ kw, const float* __restrict__ qw,
    const float* __restrict__ cb, const float* __restrict__ kb,
    const float* __restrict__ qb, unsigned short* __restrict__ fpm,
    unsigned short* __restrict__ wp, float* __restrict__ bias)
{
    const int bid = blockIdx.x;
    const int tid = threadIdx.x;

    if (bid < 520) {
        const int b = bid >= 260;
        const int rem = bid - b * 260;
        const int y = rem >> 1, xseg = rem & 1;
        const int lane = tid & 63, cg = tid >> 6;
        const int x = (xseg << 6) + lane;
        const bool inter = (y >= 1 && y <= 128);
        const float* src = feats + (((size_t)b * 256) << 14) + ((y - 1) << 7) + x;
        unsigned short* orow = fpm + ((size_t)(b * 130 + y) * 130 + 1 + x) * 256;

#pragma unroll
        for (int it = 0; it < 8; ++it) {
            const int c0 = (it << 5) + (cg << 3);
            uint4 v = {0u, 0u, 0u, 0u};
            if (inter) {
                float f0 = src[(size_t)(c0 + 0) << 14], f1 = src[(size_t)(c0 + 1) << 14];
                float f2 = src[(size_t)(c0 + 2) << 14], f3 = src[(size_t)(c0 + 3) << 14];
                float f4 = src[(size_t)(c0 + 4) << 14], f5 = src[(size_t)(c0 + 5) << 14];
                float f6 = src[(size_t)(c0 + 6) << 14], f7 = src[(size_t)(c0 + 7) << 14];
                v.x = pk2(f0, f1); v.y = pk2(f2, f3); v.z = pk2(f4, f5); v.w = pk2(f6, f7);
            }
            *(uint4*)(orow + c0) = v;
        }
        if (xseg == 0) {
            uint4 z = {0u, 0u, 0u, 0u};
            if (tid < 32)
                *(uint4*)(fpm + ((size_t)(b * 130 + y) * 130 + 0) * 256 + (tid << 3)) = z;
            else if (tid < 64)
                *(uint4*)(fpm + ((size_t)(b * 130 + y) * 130 + 129) * 256 + ((tid - 32) << 3)) = z;
        }
        return;
    }

    if (bid == 1096) {
        __shared__ float cbv[128];
        if (tid < 128) cbv[tid] = cb[tid];
        __syncthreads();
        const int oc = tid & 127, isQ = tid >> 7;
        const float* wrow = (isQ ? qw : kw) + oc * 128;
        float a = isQ ? qb[oc] : kb[oc];
        for (int j = 0; j < 128; ++j) a += wrow[j] * cbv[j];
        bias[tid] = a;
        return;
    }

    __shared__ float cvec[128][4];
    const int g = bid - 520;
    for (int idx = tid; idx < 512; idx += 256) {
        int j = idx >> 2, q = idx & 3;
        int pair = (g << 2) + q;
        int c = pair / 9, tap = pair - c * 9;
        cvec[j][q] = cw[j * 2304 + c * 9 + tap];
    }
    __syncthreads();
    const int oc = tid & 127, isQ = tid >> 7;
    const float* wrow = (isQ ? qw : kw) + oc * 128;
    float acc0 = 0.f, acc1 = 0.f, acc2 = 0.f, acc3 = 0.f;
    for (int j = 0; j < 128; ++j) {
        float wv = wrow[j];
        acc0 += wv * cvec[j][0]; acc1 += wv * cvec[j][1];
        acc2 += wv * cvec[j][2]; acc3 += wv * cvec[j][3];
    }
    float accs[4] = {acc0, acc1, acc2, acc3};
#pragma unroll
    for (int q = 0; q < 4; ++q) {
        int pair = (g << 2) + q;
        int c = pair / 9, tap = pair - c * 9;
        int chunk = c >> 5, kg = (c >> 3) & 3, i = c & 7;
        int nf = (isQ << 3) + (oc >> 4);
        int lane = (kg << 4) + (oc & 15);
        wp[((size_t)(((chunk * 9 + tap) << 4) + nf) << 9) + (lane << 3) + i] = f2bf(accs[q]);
    }
}

// ---------------------------------------------------------------------------
// conv3_k (R5-proven): fused 3x3 conv -> 256 outputs via bf16 MFMA;
// 2-deep global_load_lds staging, compiler-scheduled; epilogue via LDS obuf
// -> vectorized kT1/qT1 stores + in-block pool2 + pool4.
// ---------------------------------------------------------------------------
__global__ __launch_bounds__(256, 2) void conv3_k(
    const unsigned short* __restrict__ fpm, const unsigned short* __restrict__ wp,
    const float* __restrict__ kqbias, unsigned short* __restrict__ kT,
    unsigned short* __restrict__ qT, unsigned short* __restrict__ kT2,
    unsigned short* __restrict__ qT2, unsigned short* __restrict__ kT3,
    unsigned short* __restrict__ qT3)
{
    __shared__ __align__(16) unsigned char abuf[2][7168];
    __shared__ __align__(16) unsigned short obuf[64 * 264];

    const int tid = threadIdx.x;
    const int w = tid >> 6, lane = tid & 63;
    const int bid = blockIdx.x;
    const int b = bid >> 8, tile = bid & 255;
    const int ty0 = (tile >> 4) << 3, tx0 = (tile & 15) << 3;
    const int r = lane & 15, g = lane >> 4;

    const int sp_sub = lane >> 2, sp_o = (lane & 3) << 4;
    const int pbase = (((r >> 3) * 10) + (r & 7)) * 64 + (g << 4);
    const unsigned char* wpB = (const unsigned char*)wp + ((w << 2) << 10) + (lane << 4);

    f32x4 acc[4][4];
#pragma unroll
    for (int mi = 0; mi < 4; ++mi)
#pragma unroll
        for (int ni = 0; ni < 4; ++ni) acc[mi][ni] = (f32x4){0.f, 0.f, 0.f, 0.f};

    auto stage = [&](int chunk, int buf) {
#pragma unroll
        for (int k = 0; k < 2; ++k) {
            int i = w + (k << 2);
            if (i < 7) {
                int pl0 = (i << 4) + sp_sub;
                int y = (pl0 * 6554) >> 16;
                int x = pl0 - y * 10;
                const unsigned char* src = (const unsigned char*)fpm +
                    (((size_t)((b * 130 + ty0 + y) * 130 + tx0 + x)) << 9) +
                    (chunk << 6) + sp_o;
                gload_lds16(src, &abuf[buf][i << 10]);
            }
        }
    };

    stage(0, 0);
    __syncthreads();

    for (int chunk = 0; chunk < 8; ++chunk) {
        const unsigned char* ab = abuf[chunk & 1];
        if (chunk < 7) stage(chunk + 1, (chunk + 1) & 1);
        const unsigned char* wbase = wpB + (size_t)chunk * 147456;
#pragma unroll
        for (int tap = 0; tap < 9; ++tap) {
            const int dy = tap / 3, dx = tap % 3;
            short8 bf[4];
#pragma unroll
            for (int ni = 0; ni < 4; ++ni)
                bf[ni] = *(const short8*)(wbase + tap * 16384 + (ni << 10));
            short8 af[4];
#pragma unroll
            for (int mi = 0; mi < 4; ++mi)
                af[mi] = *(const short8*)(ab + pbase + (((2 * mi + dy) * 10 + dx) << 6));
#pragma unroll
            for (int mi = 0; mi < 4; ++mi)
#pragma unroll
                for (int ni = 0; ni < 4; ++ni)
                    acc[mi][ni] = __builtin_amdgcn_mfma_f32_16x16x32_bf16(
                        af[mi], bf[ni], acc[mi][ni], 0, 0, 0);
        }
        __syncthreads();
    }

    // epilogue: acc -> obuf (bf16, +bias)
    const int col = lane & 15;
    const int mrow0 = g << 2;
#pragma unroll
    for (int ni = 0; ni < 4; ++ni) {
        const int nf = (w << 2) + ni;
        const float bv = kqbias[(nf << 4) + col];
#pragma unroll
        for (int mi = 0; mi < 4; ++mi)
#pragma unroll
            for (int reg = 0; reg < 4; ++reg) {
                int m = mrow0 + reg;
                int pxl = ((2 * mi + (m >> 3)) << 3) + (m & 7);
                obuf[pxl * 264 + (nf << 4) + col] = f2bf(acc[mi][ni][reg] + bv);
            }
    }
    __syncthreads();

    // kT1/qT1: thread = (px, 64-oc quarter), 8x uint4
    {
        const int px = tid >> 2, q = tid & 3;
        const int gp = ((ty0 + (px >> 3)) << 7) + tx0 + (px & 7);
        const unsigned short* srow = obuf + px * 264 + (q << 6);
        unsigned short* dp = (q < 2)
            ? kT + ((((size_t)b << 14) + gp) << 7) + (q << 6)
            : qT + ((((size_t)b << 14) + gp) << 7) + ((q - 2) << 6);
#pragma unroll
        for (int j = 0; j < 8; ++j)
            *(uint4*)(dp + (j << 3)) = *(const uint4*)(srow + (j << 3));
    }

    // pool2: 16 pooled px x 16 oc-groups
    {
        const int pp = tid >> 4, ocg = tid & 15, oc0 = ocg << 4;
        const int py2 = pp >> 2, px2 = pp & 3;
        const int gp2 = (((ty0 >> 1) + py2) << 6) + (tx0 >> 1) + px2;
        unsigned short* dp = (oc0 < 128)
            ? kT2 + (((size_t)b * 4096 + gp2) << 7) + oc0
            : qT2 + (((size_t)b * 4096 + gp2) << 7) + (oc0 - 128);
#pragma unroll
        for (int h = 0; h < 2; ++h) {
            float s0=0,s1=0,s2=0,s3=0,s4=0,s5=0,s6=0,s7=0;
#pragma unroll
            for (int dy = 0; dy < 2; ++dy)
#pragma unroll
                for (int dx = 0; dx < 2; ++dx) {
                    int pxl = (((py2 << 1) + dy) << 3) + (px2 << 1) + dx;
                    uint4 v = *(const uint4*)(obuf + pxl * 264 + oc0 + (h << 3));
                    s0 += blo(v.x); s1 += bhi(v.x); s2 += blo(v.y); s3 += bhi(v.y);
                    s4 += blo(v.z); s5 += bhi(v.z); s6 += blo(v.w); s7 += bhi(v.w);
                }
            uint4 o;
            o.x = pk2(s0 * 0.25f, s1 * 0.25f); o.y = pk2(s2 * 0.25f, s3 * 0.25f);
            o.z = pk2(s4 * 0.25f, s5 * 0.25f); o.w = pk2(s6 * 0.25f, s7 * 0.25f);
            *(uint4*)(dp + (h << 3)) = o;
        }
    }

    // pool4: 4 pooled px x 16 oc-groups (threads 0..63)
    if (tid < 64) {
        const int pp = tid >> 4, ocg = tid & 15, oc0 = ocg << 4;
        const int py4 = pp >> 1, px4 = pp & 1;
        const int gp4 = (((ty0 >> 2) + py4) << 5) + (tx0 >> 2) + px4;
        unsigned short* dp = (oc0 < 128)
            ? kT3 + (((size_t)b * 1024 + gp4) << 7) + oc0
            : qT3 + (((size_t)b * 1024 + gp4) << 7) + (oc0 - 128);
#pragma unroll
        for (int h = 0; h < 2; ++h) {
            float s0=0,s1=0,s2=0,s3=0,s4=0,s5=0,s6=0,s7=0;
#pragma unroll
            for (int dy = 0; dy < 4; ++dy)
#pragma unroll
                for (int dx = 0; dx < 4; ++dx) {
                    int pxl = (((py4 << 2) + dy) << 3) + (px4 << 2) + dx;
                    uint4 v = *(const uint4*)(obuf + pxl * 264 + oc0 + (h << 3));
                    s0 += blo(v.x); s1 += bhi(v.x); s2 += blo(v.y); s3 += bhi(v.y);
                    s4 += blo(v.z); s5 += bhi(v.z); s6 += blo(v.w); s7 += bhi(v.w);
                }
            const float f = 0.0625f;
            uint4 o;
            o.x = pk2(s0 * f, s1 * f); o.y = pk2(s2 * f, s3 * f);
            o.z = pk2(s4 * f, s5 * f); o.w = pk2(s6 * f, s7 * f);
            *(uint4*)(dp + (h << 3)) = o;
        }
    }
}

// ---------------------------------------------------------------------------
// gdot_all_k: all 3 levels, 672 blocks x 512 thr. Index preload (8x int4),
// 7 random k-rows prefetched to regs, locals from XOR-swizzled LDS window,
// results buffered -> one coalesced float4 store per lane.
// ---------------------------------------------------------------------------
__global__ __launch_bounds__(512) void gdot_all_k(
    const unsigned short* __restrict__ qT1, const unsigned short* __restrict__ kT1,
    const unsigned short* __restrict__ qT2, const unsigned short* __restrict__ kT2,
    const unsigned short* __restrict__ qT3, const unsigned short* __restrict__ kT3,
    const int* __restrict__ i2, const int* __restrict__ i3, const int* __restrict__ i4,
    float* __restrict__ out)
{
    __shared__ __align__(16) unsigned char kwin[144 * 256];

    const int raw = blockIdx.x;
    const int bid = (raw & 7) * 84 + (raw >> 3);

    const unsigned short *qT, *kT;
    const int* inds;
    int n, wshift, tpbsh, twsh, off;
    if (bid < 512) {
        qT = qT1; kT = kT1; inds = i2; n = 16384; wshift = 7; tpbsh = 8; twsh = 4; off = 0;
    } else if (bid < 640) {
        qT = qT2; kT = kT2; inds = i3; n = 4096;  wshift = 6; tpbsh = 6; twsh = 3; off = 16384;
    } else {
        qT = qT3; kT = kT3; inds = i4; n = 1024;  wshift = 5; tpbsh = 4; twsh = 2; off = 20480;
    }
    const int lb   = bid - ((bid < 512) ? 0 : (bid < 640) ? 512 : 640);
    const int b    = lb >> tpbsh;
    const int tile = lb & ((1 << tpbsh) - 1);
    const int ty0  = (tile >> twsh) << 3;
    const int tx0  = (tile & ((1 << twsh) - 1)) << 3;
    const int W    = 1 << wshift, Wm1 = W - 1;
    const int ry0  = ty0 - 2, cx0 = tx0 - 2;

    const int tid   = threadIdx.x;
    const int pxl   = tid >> 3;
    const int slice = tid & 7;
    const int py = pxl >> 3, px = pxl & 7;
    const int nid = ((ty0 + py) << wshift) + tx0 + px;

    for (int idx = tid; idx < 2304; idx += 512) {
        int slot = idx >> 4, w16 = idx & 15;
        int sy = ry0 + slot / 12, sx = cx0 + slot % 12;
        sy = min(max(sy, 0), Wm1); sx = min(max(sx, 0), Wm1);
        uint4 v = *(const uint4*)(kT + ((size_t)(b * n + (sy << wshift) + sx) * 128) + (w16 << 3));
        *(uint4*)&kwin[slot * 256 + ((w16 ^ (slot & 7)) << 4)] = v;
    }

    float qr[16];
    {
        const uint4* qp = (const uint4*)(qT + ((size_t)(b * n + nid) * 128) + (slice << 4));
        uint4 q0 = qp[0], q1 = qp[1];
        qr[0] = blo(q0.x); qr[1] = bhi(q0.x); qr[2] = blo(q0.y); qr[3] = bhi(q0.y);
        qr[4] = blo(q0.z); qr[5] = bhi(q0.z); qr[6] = blo(q0.w); qr[7] = bhi(q0.w);
        qr[8] = blo(q1.x); qr[9] = bhi(q1.x); qr[10] = blo(q1.y); qr[11] = bhi(q1.y);
        qr[12] = blo(q1.z); qr[13] = bhi(q1.z); qr[14] = blo(q1.w); qr[15] = bhi(q1.w);
    }
    __syncthreads();

    const int* irow = inds + ((size_t)(b * n + nid) << 5);
    int ia[32];
    {
        const int4* ip = (const int4*)irow;
#pragma unroll
        for (int j = 0; j < 8; ++j) {
            int4 v = ip[j];
            ia[4 * j] = v.x; ia[4 * j + 1] = v.y; ia[4 * j + 2] = v.z; ia[4 * j + 3] = v.w;
        }
    }

    uint4 rk0[7], rk1[7];
#pragma unroll
    for (int rr = 0; rr < 7; ++rr) {
        const uint4* kp = (const uint4*)(kT + (((size_t)(b * n + ia[25 + rr])) << 7) + (slice << 4));
        rk0[rr] = kp[0]; rk1[rr] = kp[1];
    }

    const int w2 = slice << 1;
    float res4[4] = {0.f, 0.f, 0.f, 0.f};
    float* orow = out + (((size_t)b * NTOT + off + nid) << 5);

#pragma unroll
    for (int s = 0; s < 32; ++s) {
        uint4 k0, k1;
        if (s < 25) {
            int ind = ia[s];
            int iy = ind >> wshift, ix = ind & Wm1;
            int slot = (iy - ry0) * 12 + (ix - cx0);
            int sw = slot & 7;
            const unsigned char* base2 = kwin + slot * 256;
            k0 = *(const uint4*)(base2 + ((w2 ^ sw) << 4));
            k1 = *(const uint4*)(base2 + (((w2 + 1) ^ sw) << 4));
        } else {
            k0 = rk0[s - 25]; k1 = rk1[s - 25];
        }
        float a = qr[0] * blo(k0.x) + qr[1] * bhi(k0.x)
                + qr[2] * blo(k0.y) + qr[3] * bhi(k0.y)
                + qr[4] * blo(k0.z) + qr[5] * bhi(k0.z)
                + qr[6] * blo(k0.w) + qr[7] * bhi(k0.w)
                + qr[8] * blo(k1.x) + qr[9] * bhi(k1.x)
                + qr[10] * blo(k1.y) + qr[11] * bhi(k1.y)
                + qr[12] * blo(k1.z) + qr[13] * bhi(k1.z)
                + qr[14] * blo(k1.w) + qr[15] * bhi(k1.w);
        a += __shfl_xor(a, 1);
        a += __shfl_xor(a, 2);
        a += __shfl_xor(a, 4);
        if ((s >> 2) == slice) res4[s & 3] = a * SCALE;
    }
    *(float4*)(orow + (slice << 2)) = *(const float4*)res4;
}

// ---------------------------------------------------------------------------
extern "C" void kernel_launch(void* const* d_in, const int* in_sizes, int n_in,
                              void* d_out, int out_size, void* d_ws, size_t ws_size,
                              hipStream_t stream)
{
    const float* feats = (const float*)d_in[0];
    const float* cw    = (const float*)d_in[1];
    const float* cb    = (const float*)d_in[2];
    const float* kw    = (const float*)d_in[3];
    const float* kb    = (const float*)d_in[4];
    const float* qw    = (const float*)d_in[5];
    const float* qb    = (const float*)d_in[6];
    const int*   i2    = (const int*)d_in[7];
    const int*   i3    = (const int*)d_in[8];
    const int*   i4    = (const int*)d_in[9];
    float* out = (float*)d_out;

    char* ws = (char*)d_ws;
    unsigned short* wp   = (unsigned short*)ws;                 // 1,179,648 B
    float*          bias = (float*)(ws + 1179648);              //     1,024 B
    unsigned short* fpm  = (unsigned short*)(ws + 1180672);     // 17,305,600 B
    unsigned short* kT1  = (unsigned short*)(ws + 18624512);    // 8,388,608 B
    unsigned short* qT1  = kT1 + 4194304;
    unsigned short* kT2  = qT1 + 4194304;                       // 2,097,152 B
    unsigned short* qT2  = kT2 + 1048576;
    unsigned short* kT3  = qT2 + 1048576;                       //   524,288 B
    unsigned short* qT3  = kT3 + 262144;

    tp_k<<<dim3(1097), 256, 0, stream>>>(feats, cw, kw, qw, cb, kb, qb,
                                         fpm, wp, bias);
    conv3_k<<<dim3(512), 256, 0, stream>>>(fpm, wp, bias, kT1, qT1,
                                           kT2, qT2, kT3, qT3);
    gdot_all_k<<<dim3(672), 512, 0, stream>>>(qT1, kT1, qT2, kT2, qT3, kT3,
                                              i2, i3, i4, out);
}